// Round 4
// baseline (400.305 us; speedup 1.0000x reference)
//
#include <hip/hip_runtime.h>
#include <hip/hip_bf16.h>

typedef __bf16 bf16_t;
typedef __attribute__((ext_vector_type(8))) __bf16 bf16x8;
typedef __attribute__((ext_vector_type(4))) float f32x4;
typedef __attribute__((ext_vector_type(8))) unsigned short ushort8v;

#define MFMA16(a, b, c) __builtin_amdgcn_mfma_f32_16x16x32_bf16((a), (b), (c), 0, 0, 0)
#define BC8(x) __builtin_bit_cast(bf16x8, (x))

__device__ __forceinline__ unsigned short f2bf(float f) {
    bf16_t b = (bf16_t)f;
    return __builtin_bit_cast(unsigned short, b);
}

__device__ __forceinline__ void gload16(const void* g, void* l) {
    __builtin_amdgcn_global_load_lds(
        (const __attribute__((address_space(1))) void*)g,
        (__attribute__((address_space(3))) void*)l,
        16, 0, 0);
}

// ---------- fp32 -> bf16 elementwise convert (for X) ----------
__global__ __launch_bounds__(256) void cvtx(const float* __restrict__ src,
                                            bf16_t* __restrict__ dst) {
    size_t i = ((size_t)blockIdx.x * 256 + threadIdx.x) * 8;
    f32x4 v0 = *(const f32x4*)(src + i);
    f32x4 v1 = *(const f32x4*)(src + i + 4);
    bf16x8 o;
    o[0] = (bf16_t)v0[0]; o[1] = (bf16_t)v0[1];
    o[2] = (bf16_t)v0[2]; o[3] = (bf16_t)v0[3];
    o[4] = (bf16_t)v1[0]; o[5] = (bf16_t)v1[1];
    o[6] = (bf16_t)v1[2]; o[7] = (bf16_t)v1[3];
    *(bf16x8*)(dst + i) = o;
}

// ---------- batched 64x64 transpose + fp32->bf16 convert ----------
__global__ __launch_bounds__(256) void transcvt64(const float* __restrict__ src,
                                                  unsigned short* __restrict__ dst,
                                                  int R, int C) {
    __shared__ __align__(16) unsigned short tile[64][66];
    size_t off = (size_t)blockIdx.z * R * C;
    const float* s = src + off;
    unsigned short* d = dst + off;
    int tr = blockIdx.y * 64, tc = blockIdx.x * 64;
    int tid = threadIdx.x;
    int lr = tid >> 4;
    int lc = (tid & 15) * 4;
#pragma unroll
    for (int p = 0; p < 4; ++p) {
        int r = p * 16 + lr;
        f32x4 v = *(const f32x4*)(s + (size_t)(tr + r) * C + tc + lc);
        tile[r][lc + 0] = f2bf(v[0]); tile[r][lc + 1] = f2bf(v[1]);
        tile[r][lc + 2] = f2bf(v[2]); tile[r][lc + 3] = f2bf(v[3]);
    }
    __syncthreads();
#pragma unroll
    for (int q = 0; q < 2; ++q) {
        int item = q * 256 + tid;
        int oc = item >> 3;            // column 0..63
        int rb = (item & 7) * 8;       // row octet
        ushort8v v;
#pragma unroll
        for (int t = 0; t < 8; ++t) v[t] = tile[rb + t][oc];
        *(ushort8v*)(d + (size_t)(tc + oc) * R + tr + rb) = v;
    }
}

// =====================================================================
// Ring-buffered single-barrier-per-half GEMMs.
// LDS = 4 ring slots x 32KB (one K=32 half-tile). Compute half h, stage
// half h+3. Fragment reads are inline-asm ds_read_b128 with f32x4 outputs
// (opaque to compiler aliasing -> no conservative vmcnt drains before
// reads), ordered by counted lgkmcnt + sched_barrier(0) (rule #18).
// One s_barrier per half.
// Safety ledger (per half h):
//   slot(h) staged-visible: each wave's VMW in H(h-1) forces its own
//     stage(h) loads; end-barrier of H(h-1) orders cross-wave.
//   slot overwrite (STG h+3 -> slot h-1): every wave's lgkmcnt(0) before
//     its second MFMA cluster in H(h-1) completes all slot(h-1) reads;
//     end-barrier of H(h-1) precedes any wave's STG in H(h).
//   DS queue completes in-order per wave -> lgkmcnt(4) leaves exactly
//     the 4 newest reads outstanding.
// =====================================================================

#define PH_FENCE __builtin_amdgcn_sched_barrier(0)
#define LGKMN(n) { asm volatile("s_waitcnt lgkmcnt(" #n ")" ::: "memory"); \
                   __builtin_amdgcn_sched_barrier(0); }
#define VMW(n) asm volatile("s_waitcnt vmcnt(" #n ")" ::: "memory")
#define DSR(dst, a, OFF) asm volatile("ds_read_b128 %0, %1 " OFF : "=v"(dst) : "v"(a))

// ---------- GEMM1 fused: Hh = silu(X*W1) * (X*W3) ----------
// Tile 256(M) x 128(N), 8 waves = 4M x 2N, per-wave 64x64 dual (U,V).
// Slot bytes: A rows0-127 [0,8192), A rows128-255 [8192,16384),
// B1 [16384,24576), B3 [24576,32768). Slot stride 32768 B.
__global__ __launch_bounds__(512, 2) void gemm13(const bf16_t* __restrict__ Xb,
                                                 const bf16_t* __restrict__ W1t,
                                                 const bf16_t* __restrict__ W3t,
                                                 bf16_t* __restrict__ Hh,
                                                 int row_base) {
    const int K = 1024, N = 2048;
    int nwg = gridDim.x, id = blockIdx.x;
    if ((nwg & 7) == 0) id = (id & 7) * (nwg >> 3) + (id >> 3);  // XCD swizzle
    int nbx = nwg >> 4;
    int bx = id % nbx, by = id / nbx;      // col-major: co-resident share W-panels
    int row0 = bx * 256, col0 = by * 128;
    int seg = ((row_base + row0) & 2047) >> 9;
    const bf16_t* Ag  = Xb + (size_t)row0 * K;
    const bf16_t* B1g = W1t + ((size_t)seg * N + col0) * K;
    const bf16_t* B3g = W3t + ((size_t)seg * N + col0) * K;

    __shared__ __align__(16) bf16_t smem[65536];     // 4 x 32KB slots

    int tid = threadIdx.x, lane = tid & 63, w = tid >> 6;
    int wm = w >> 1, wn = w & 1;
    int quad = lane >> 4, l16 = lane & 15;

    int r0 = 2 * (tid >> 3) + ((tid >> 2) & 1);
    int c0 = (tid & 3) ^ ((tid >> 3) & 3);
    int offG  = r0 * K + c0 * 8;
    int offG2 = offG + 128 * K;

    int sigRd = ((l16 & 1) << 2) | (quad ^ ((l16 >> 1) & 3));
    int rdAB = ((wm * 32 + (l16 >> 1)) * 64 + sigRd * 8) * 2;   // byte addr, A region
    int rdBB = ((wn * 32 + (l16 >> 1)) * 64 + sigRd * 8) * 2;   // byte addr, B region

    f32x4 accU[4][4], accV[4][4];
    f32x4 z = {0.f, 0.f, 0.f, 0.f};
#pragma unroll
    for (int i = 0; i < 4; ++i)
#pragma unroll
        for (int j = 0; j < 4; ++j) { accU[i][j] = z; accV[i][j] = z; }

    f32x4 af[4], bU[4], bV[4];

#define STG13(slot, hh) { bf16_t* d_ = smem + (slot) * 16384; const int kg_ = (hh) * 32; \
    gload16(Ag + kg_ + offG,  d_ + tid * 8); \
    gload16(Ag + kg_ + offG2, d_ + 4096 + tid * 8); \
    gload16(B1g + kg_ + offG, d_ + 8192 + tid * 8); \
    gload16(B3g + kg_ + offG, d_ + 12288 + tid * 8); }

#define HALF13(slot, STG, WAIT) {                                               \
    PH_FENCE;                                                                   \
    STG;                                                                        \
    int aA_ = (slot) * 32768 + rdAB;                                            \
    int aB_ = (slot) * 32768 + rdBB;                                            \
    DSR(af[0], aA_, "offset:0");     DSR(af[1], aA_, "offset:1024");            \
    DSR(af[2], aA_, "offset:2048");  DSR(af[3], aA_, "offset:3072");            \
    DSR(bU[0], aB_, "offset:16384"); DSR(bU[1], aB_, "offset:17408");           \
    DSR(bU[2], aB_, "offset:18432"); DSR(bU[3], aB_, "offset:19456");           \
    DSR(bV[0], aB_, "offset:24576"); DSR(bV[1], aB_, "offset:25600");           \
    DSR(bV[2], aB_, "offset:26624"); DSR(bV[3], aB_, "offset:27648");           \
    LGKMN(4);                                                                   \
    __builtin_amdgcn_s_setprio(1);                                              \
    _Pragma("unroll")                                                           \
    for (int i_ = 0; i_ < 4; ++i_)                                              \
        _Pragma("unroll")                                                       \
        for (int j_ = 0; j_ < 4; ++j_)                                          \
            accU[i_][j_] = MFMA16(BC8(af[i_]), BC8(bU[j_]), accU[i_][j_]);      \
    __builtin_amdgcn_s_setprio(0);                                              \
    LGKMN(0);                                                                   \
    __builtin_amdgcn_s_setprio(1);                                              \
    _Pragma("unroll")                                                           \
    for (int i_ = 0; i_ < 4; ++i_)                                              \
        _Pragma("unroll")                                                       \
        for (int j_ = 0; j_ < 4; ++j_)                                          \
            accV[i_][j_] = MFMA16(BC8(af[i_]), BC8(bV[j_]), accV[i_][j_]);      \
    __builtin_amdgcn_s_setprio(0);                                              \
    WAIT;                                                                       \
    __builtin_amdgcn_s_barrier(); }

    // prologue: halves 0..2 in flight (12 loads); force half 0's 4, keep 8
    STG13(0, 0); STG13(1, 1); STG13(2, 2);
    VMW(8);
    __builtin_amdgcn_s_barrier();

#pragma unroll 1
    for (int h = 0; h < 28; h += 4) {           // halves 0..27, stage 3..30
        HALF13(0, STG13(3, h + 3), VMW(8));
        HALF13(1, STG13(0, h + 4), VMW(8));
        HALF13(2, STG13(1, h + 5), VMW(8));
        HALF13(3, STG13(2, h + 6), VMW(8));
    }
    HALF13(0, STG13(3, 31), VMW(8));            // half 28, stage 31
    HALF13(1, , VMW(4));                        // half 29 -> forces slot 30
    HALF13(2, , VMW(0));                        // half 30 -> forces slot 31
    HALF13(3, , );                              // half 31

    // Epilogue: silu(U)*V -> LDS bf16 [256][136] -> full-line stores
    __syncthreads();
    bf16_t* Ct = smem;
#pragma unroll
    for (int i = 0; i < 4; ++i)
#pragma unroll
        for (int j = 0; j < 4; ++j) {
            int r = wm * 64 + i * 16 + quad * 4;
            int c = wn * 64 + j * 16 + l16;
#pragma unroll
            for (int t = 0; t < 4; ++t) {
                float u = accU[i][j][t];
                float v = accV[i][j][t];
                float h = (u / (1.f + __expf(-u))) * v;
                Ct[(r + t) * 136 + c] = (bf16_t)h;
            }
        }
    __syncthreads();
#pragma unroll
    for (int s = 0; s < 8; ++s) {
        int r = s * 32 + (tid >> 4);
        int cb = (tid & 15) * 8;
        bf16x8 v = *(const bf16x8*)(Ct + r * 136 + cb);
        *(bf16x8*)(Hh + (size_t)(row0 + r) * N + col0 + cb) = v;
    }
#undef HALF13
#undef STG13
}

// ---------- GEMM2: Out = Hh * W2 ----------
// Tile 256(M) x 256(N), 8 waves = 2M x 4N, per-wave 128x64.
// Slot bytes: A [0,16384) (row-half via +8192), B [16384,32768).
__global__ __launch_bounds__(512, 2) void gemm2k(const bf16_t* __restrict__ Hh,
                                                 const bf16_t* __restrict__ W2t,
                                                 float* __restrict__ Outc,
                                                 int row_base) {
    const int K = 2048, N = 1024;
    int nwg = gridDim.x, id = blockIdx.x;
    if ((nwg & 7) == 0) id = (id & 7) * (nwg >> 3) + (id >> 3);
    int nbx = nwg >> 2;
    int bx = id % nbx, by = id / nbx;
    int row0 = bx * 256, col0 = by * 256;
    int seg = ((row_base + row0) & 2047) >> 9;
    const bf16_t* Ag = Hh + (size_t)row0 * K;
    const bf16_t* Bg = W2t + ((size_t)seg * N + col0) * K;

    __shared__ __align__(16) bf16_t smem[65536];

    int tid = threadIdx.x, lane = tid & 63, w = tid >> 6;
    int wm = w >> 2, wn = w & 3;
    int quad = lane >> 4, l16 = lane & 15;

    int r0 = 2 * (tid >> 3) + ((tid >> 2) & 1);
    int c0 = (tid & 3) ^ ((tid >> 3) & 3);
    int offG  = r0 * K + c0 * 8;
    int offG2 = offG + 128 * K;

    int sigRd = ((l16 & 1) << 2) | (quad ^ ((l16 >> 1) & 3));
    int rdAB = ((wm * 64 + (l16 >> 1)) * 64 + sigRd * 8) * 2;   // + mq*4096B + i*1024B
    int rdBB = ((wn * 32 + (l16 >> 1)) * 64 + sigRd * 8) * 2;   // + 16384B + j*1024B

    f32x4 acc[8][4];
    f32x4 z = {0.f, 0.f, 0.f, 0.f};
#pragma unroll
    for (int i = 0; i < 8; ++i)
#pragma unroll
        for (int j = 0; j < 4; ++j) acc[i][j] = z;

    f32x4 af[4], ag[4], bfr[4];

#define STG2(slot, hh) { bf16_t* d_ = smem + (slot) * 16384; const int kg_ = (hh) * 32; \
    gload16(Ag + kg_ + offG,  d_ + tid * 8); \
    gload16(Ag + kg_ + offG2, d_ + 4096 + tid * 8); \
    gload16(Bg + kg_ + offG,  d_ + 8192 + tid * 8); \
    gload16(Bg + kg_ + offG2, d_ + 12288 + tid * 8); }

#define HALF2(slot, STG, WAIT) {                                                \
    PH_FENCE;                                                                   \
    STG;                                                                        \
    int aA_ = (slot) * 32768 + rdAB;                                            \
    int aB_ = (slot) * 32768 + rdBB;                                            \
    DSR(af[0], aA_, "offset:0");      DSR(af[1], aA_, "offset:1024");           \
    DSR(af[2], aA_, "offset:2048");   DSR(af[3], aA_, "offset:3072");           \
    DSR(bfr[0], aB_, "offset:16384"); DSR(bfr[1], aB_, "offset:17408");         \
    DSR(bfr[2], aB_, "offset:18432"); DSR(bfr[3], aB_, "offset:19456");         \
    DSR(ag[0], aA_, "offset:4096");   DSR(ag[1], aA_, "offset:5120");           \
    DSR(ag[2], aA_, "offset:6144");   DSR(ag[3], aA_, "offset:7168");           \
    LGKMN(4);                                                                   \
    __builtin_amdgcn_s_setprio(1);                                              \
    _Pragma("unroll")                                                           \
    for (int i_ = 0; i_ < 4; ++i_)                                              \
        _Pragma("unroll")                                                       \
        for (int j_ = 0; j_ < 4; ++j_)                                          \
            acc[i_][j_] = MFMA16(BC8(af[i_]), BC8(bfr[j_]), acc[i_][j_]);       \
    __builtin_amdgcn_s_setprio(0);                                              \
    LGKMN(0);                                                                   \
    __builtin_amdgcn_s_setprio(1);                                              \
    _Pragma("unroll")                                                           \
    for (int i_ = 0; i_ < 4; ++i_)                                              \
        _Pragma("unroll")                                                       \
        for (int j_ = 0; j_ < 4; ++j_)                                          \
            acc[4 + i_][j_] = MFMA16(BC8(ag[i_]), BC8(bfr[j_]), acc[4 + i_][j_]); \
    __builtin_amdgcn_s_setprio(0);                                              \
    WAIT;                                                                       \
    __builtin_amdgcn_s_barrier(); }

    STG2(0, 0); STG2(1, 1); STG2(2, 2);
    VMW(8);
    __builtin_amdgcn_s_barrier();

#pragma unroll 1
    for (int h = 0; h < 60; h += 4) {           // halves 0..59, stage 3..62
        HALF2(0, STG2(3, h + 3), VMW(8));
        HALF2(1, STG2(0, h + 4), VMW(8));
        HALF2(2, STG2(1, h + 5), VMW(8));
        HALF2(3, STG2(2, h + 6), VMW(8));
    }
    HALF2(0, STG2(3, 63), VMW(8));              // half 60, stage 63
    HALF2(1, , VMW(4));                         // half 61
    HALF2(2, , VMW(0));                         // half 62
    HALF2(3, , );                               // half 63

    // Epilogue: 4 x 64-row passes through f32 LDS [64][260], 1KB/row stores
    __syncthreads();
    float* smemf = (float*)smem;
    for (int pass = 0; pass < 4; ++pass) {
        if (pass) __syncthreads();
        if (wm == (pass >> 1)) {
            int mq = pass & 1;
#pragma unroll
            for (int i = 0; i < 4; ++i)
#pragma unroll
                for (int j = 0; j < 4; ++j) {
                    int r = i * 16 + quad * 4;
                    int c = wn * 64 + j * 16 + l16;
#pragma unroll
                    for (int t = 0; t < 4; ++t)
                        smemf[(r + t) * 260 + c] = acc[mq * 4 + i][j][t];
                }
        }
        __syncthreads();
#pragma unroll
        for (int s = 0; s < 8; ++s) {
            int r = s * 8 + w;
            f32x4 v = *(const f32x4*)(smemf + r * 260 + lane * 4);
            *(f32x4*)(Outc + (size_t)(row0 + pass * 64 + r) * N + col0 + lane * 4) = v;
        }
    }
#undef HALF2
#undef STG2
}

extern "C" void kernel_launch(void* const* d_in, const int* in_sizes, int n_in,
                              void* d_out, int out_size, void* d_ws, size_t ws_size,
                              hipStream_t stream) {
    const float* x  = (const float*)d_in[0];   // fp32 [8,2048,1024]
    const float* w1 = (const float*)d_in[1];   // fp32 [4,1024,2048]
    const float* w3 = (const float*)d_in[2];   // fp32 [4,1024,2048]
    const float* w2 = (const float*)d_in[3];   // fp32 [4,2048,1024]
    float* out = (float*)d_out;                // fp32 [8,2048,1024]

    const size_t WSEG = (size_t)4 * 1024 * 2048;
    bf16_t* w1t = (bf16_t*)d_ws;
    bf16_t* w3t = w1t + WSEG;
    bf16_t* w2t = w3t + WSEG;
    bf16_t* dyn = w2t + WSEG;

    transcvt64<<<dim3(32, 16, 4), 256, 0, stream>>>(w1, (unsigned short*)w1t, 1024, 2048);
    transcvt64<<<dim3(32, 16, 4), 256, 0, stream>>>(w3, (unsigned short*)w3t, 1024, 2048);
    transcvt64<<<dim3(16, 32, 4), 256, 0, stream>>>(w2, (unsigned short*)w2t, 2048, 1024);

    const int TOTAL_ROWS = 16384;
    size_t wbytes = 3 * WSEG * sizeof(bf16_t);
    size_t avail = (ws_size > wbytes) ? ws_size - wbytes : 0;
    int chunk_rows = TOTAL_ROWS;
    while (chunk_rows > 256 && (size_t)chunk_rows * 6144 > avail)
        chunk_rows >>= 1;

    for (int rb = 0; rb < TOTAL_ROWS; rb += chunk_rows) {
        bf16_t* Xb = dyn;
        bf16_t* Hh = dyn + (size_t)chunk_rows * 1024;
        cvtx<<<chunk_rows / 2, 256, 0, stream>>>(x + (size_t)rb * 1024, Xb);
        gemm13<<<(chunk_rows / 256) * 16, 512, 0, stream>>>(Xb, w1t, w3t, Hh, rb);
        gemm2k<<<(chunk_rows / 256) * 4, 512, 0, stream>>>(Hh, w2t, out + (size_t)rb * 1024, rb);
    }
}